// Round 13
// baseline (184.800 us; speedup 1.0000x reference)
//
#include <hip/hip_runtime.h>
#include <math.h>

// Problem constants
#define NB 4
#define TT 256
#define DMODEL 1024
#define NE 16
#define DLQ 64
#define NH 4
#define HD 16
#define SEQL 17
#define NTOK 1024   // NB*TT

// Workspace layout (float offsets). ws is ~268 MB; regions are private (no
// overlays, no ordering hazards).
static constexpr size_t WS_EF    = 0;          // 1024x1024 fp32 ef partial P0
static constexpr size_t WS_AH    = 1048576;    // x hi bf16 plane, frag-swizzled
static constexpr size_t WS_AL    = 1572864;    // x lo
static constexpr size_t WS_BH    = 2097152;    // w_down hi
static constexpr size_t WS_BL    = 2621440;    // w_down lo
static constexpr size_t WS_P1    = 3145728;    // K-split partial P1
static constexpr size_t WS_ACT   = 4194304;    // act bf16 [2048][64]
static constexpr size_t WS_AIWFH = 4259840;    // attn_in_w hi frags (12288 sh)
static constexpr size_t WS_AIWFL = 4265984;    // attn_in_w lo frags
static constexpr size_t WS_AOWFH = 4272128;    // attn_out_w hi frags (4096 sh)
static constexpr size_t WS_AOWFL = 4274176;    // attn_out_w lo frags
static constexpr size_t WS_PR    = 4308992;    // 1024x16 probs
static constexpr size_t WS_TI    = 4325376;    // 1024 packed ints: t0 | t1<<8
static constexpr size_t WS_GCTX  = 4326400;    // 4x64
static constexpr size_t WS_GB    = 4326656;    // 4x16

typedef __attribute__((ext_vector_type(8))) short short8;
typedef __attribute__((ext_vector_type(4))) float f32x4;

__device__ __forceinline__ float gelu_exact(float x) {
    return 0.5f * x * (1.0f + erff(x * 0.70710678118654752f));
}

__device__ __forceinline__ unsigned short f2bf(float f) {
    unsigned int u = __float_as_uint(f);
    unsigned int r = (u + 0x7fffu + ((u >> 16) & 1u)) >> 16;
    return (unsigned short)r;
}
__device__ __forceinline__ float bf2f(unsigned short h) {
    return __uint_as_float(((unsigned int)h) << 16);
}

// DPP row_ror all-reduce within 16-lane rows: VALU pipe, zero LDS ops.
#define DPP_ADD(v, ctrl) { int _m = __builtin_amdgcn_update_dpp(0, __float_as_int(v), ctrl, 0xF, 0xF, true); \
                           v += __int_as_float(_m); }
__device__ __forceinline__ float rsum16(float v) {
    DPP_ADD(v, 0x128);  // row_ror:8
    DPP_ADD(v, 0x124);  // row_ror:4
    DPP_ADD(v, 0x122);  // row_ror:2
    DPP_ADD(v, 0x121);  // row_ror:1
    return v;
}
__device__ __forceinline__ float rsum64(float v) {
    v = rsum16(v);
    v += __shfl_xor(v, 16);
    v += __shfl_xor(v, 32);
    return v;
}

// K0 (fused): blocks 0..1023 split x / w_down into hi/lo bf16 frag-swizzled
// planes; blocks 1024..1027: global-ctx MLP per batch (reads x directly —
// no XPART intermediate; 4-row groups give 4-way ILP on the load->rsum64
// chains that made r12's wave-iteration version a 35 us serial tail);
// block 1028 builds the attn weight frag planes.
__global__ __launch_bounds__(256) void k_prep(const float* __restrict__ x,
                                              const float* __restrict__ wdn,
                                              const float* __restrict__ aiw,
                                              const float* __restrict__ aow,
                                              const float* __restrict__ gp_w,
                                              const float* __restrict__ gp_b,
                                              const float* __restrict__ g1_w,
                                              const float* __restrict__ g1_b,
                                              const float* __restrict__ g2_w,
                                              const float* __restrict__ g2_b,
                                              float* __restrict__ ws) {
    __shared__ float xm[DMODEL];
    __shared__ float gc[DLQ];
    __shared__ float gb1[128];
    int bi = blockIdx.x;
    int tid = threadIdx.x;
    if (bi < 1024) {
        int which = bi >> 9;   // 0: x, 1: w_down
        int t = (bi & 511) * 256 + tid;
        int row = t >> 7;
        int col0 = (t & 127) * 8;
        const float* src = which ? wdn : x;
        unsigned short* hp = (unsigned short*)(ws + (which ? WS_BH : WS_AH));
        unsigned short* lp = (unsigned short*)(ws + (which ? WS_BL : WS_AL));
        float4 v0 = *(const float4*)(src + (size_t)row * DMODEL + col0);
        float4 v1 = *(const float4*)(src + (size_t)row * DMODEL + col0 + 4);
        float vv[8] = {v0.x, v0.y, v0.z, v0.w, v1.x, v1.y, v1.z, v1.w};
        unsigned short h8[8], l8[8];
#pragma unroll
        for (int j = 0; j < 8; ++j) {
            h8[j] = f2bf(vv[j]);
            l8[j] = f2bf(vv[j] - bf2f(h8[j]));
        }
        int nb = row >> 6, kb = col0 >> 6;
        int st = (row & 63) >> 4;
        int ks = (col0 & 63) >> 5;
        int ln = (row & 15) + (((col0 >> 3) & 3) << 4);
        size_t off = (size_t)(nb * 16 + kb) * 4096 + st * 1024 + ks * 512 + ln * 8;
        *(short8*)(hp + off) = *(short8*)h8;
        *(short8*)(lp + off) = *(short8*)l8;
    } else if (bi < 1028) {
        int b = bi - 1024;
        int wv = tid >> 6, l = tid & 63;
        // xmean: thread t owns columns t*4..t*4+3; 256 independent loads
        {
            const float* xb = x + (size_t)b * TT * DMODEL + tid * 4;
            float4 a = {0.f, 0.f, 0.f, 0.f};
#pragma unroll 4
            for (int t2 = 0; t2 < TT; ++t2) {
                float4 v = *(const float4*)(xb + (size_t)t2 * DMODEL);
                a.x += v.x; a.y += v.y; a.z += v.z; a.w += v.w;
            }
            const float inv_t = 1.0f / (float)TT;
            xm[tid * 4 + 0] = a.x * inv_t;
            xm[tid * 4 + 1] = a.y * inv_t;
            xm[tid * 4 + 2] = a.z * inv_t;
            xm[tid * 4 + 3] = a.w * inv_t;
        }
        __syncthreads();
        // gctx: wave wv rows wv*16..+15 in groups of 4 (independent dots+reduces)
        {
            const float* xp = xm + l * 16;
            float4 xv0 = *(const float4*)(xp);
            float4 xv1 = *(const float4*)(xp + 4);
            float4 xv2 = *(const float4*)(xp + 8);
            float4 xv3 = *(const float4*)(xp + 12);
            for (int rq = 0; rq < 4; ++rq) {
                int o = wv * 16 + rq * 4;
                float s[4];
#pragma unroll
                for (int r = 0; r < 4; ++r) {
                    const float* wr = gp_w + (size_t)(o + r) * DMODEL + l * 16;
                    float4 w0 = *(const float4*)(wr);
                    float4 w1 = *(const float4*)(wr + 4);
                    float4 w2 = *(const float4*)(wr + 8);
                    float4 w3 = *(const float4*)(wr + 12);
                    s[r] = w0.x * xv0.x + w0.y * xv0.y + w0.z * xv0.z + w0.w * xv0.w +
                           w1.x * xv1.x + w1.y * xv1.y + w1.z * xv1.z + w1.w * xv1.w +
                           w2.x * xv2.x + w2.y * xv2.y + w2.z * xv2.z + w2.w * xv2.w +
                           w3.x * xv3.x + w3.y * xv3.y + w3.z * xv3.z + w3.w * xv3.w;
                }
#pragma unroll
                for (int r = 0; r < 4; ++r) s[r] = rsum64(s[r]);
                if (l == 0) {
#pragma unroll
                    for (int r = 0; r < 4; ++r) {
                        float v = s[r] + gp_b[o + r];
                        gc[o + r] = v;
                        ws[WS_GCTX + b * DLQ + o + r] = v;
                    }
                }
            }
        }
        __syncthreads();
        // g1: wave wv rows wv*32..+31 in groups of 4
        {
            float gcl = gc[l];
            for (int rq = 0; rq < 8; ++rq) {
                int o = wv * 32 + rq * 4;
                float s[4];
#pragma unroll
                for (int r = 0; r < 4; ++r) s[r] = gcl * g1_w[(size_t)(o + r) * DLQ + l];
#pragma unroll
                for (int r = 0; r < 4; ++r) s[r] = rsum64(s[r]);
                if (l == 0) {
#pragma unroll
                    for (int r = 0; r < 4; ++r) gb1[o + r] = gelu_exact(s[r] + g1_b[o + r]);
                }
            }
        }
        __syncthreads();
        // g2: wave wv rows wv*4..+3 (one group of 4)
        {
            float v0 = gb1[l * 2], v1 = gb1[l * 2 + 1];
            int o = wv * 4;
            float s[4];
#pragma unroll
            for (int r = 0; r < 4; ++r)
                s[r] = v0 * g2_w[(size_t)(o + r) * 128 + l * 2] +
                       v1 * g2_w[(size_t)(o + r) * 128 + l * 2 + 1];
#pragma unroll
            for (int r = 0; r < 4; ++r) s[r] = rsum64(s[r]);
            if (l == 0) {
#pragma unroll
                for (int r = 0; r < 4; ++r) ws[WS_GB + b * NE + o + r] = s[r] + g2_b[o + r];
            }
        }
    } else {
        unsigned short* fh = (unsigned short*)(ws + WS_AIWFH);
        unsigned short* fl = (unsigned short*)(ws + WS_AIWFL);
        for (int idx = tid; idx < 12 * 2 * 64; idx += 256) {
            int nt = idx >> 7, kf = (idx >> 6) & 1, l = idx & 63;
            int row = nt * 16 + (l & 15);
            int k = kf * 32 + ((l >> 4) << 3);
            const float* src = aiw + (size_t)row * DLQ + k;
            unsigned short h8[8], l8[8];
#pragma unroll
            for (int j = 0; j < 8; ++j) {
                h8[j] = f2bf(src[j]);
                l8[j] = f2bf(src[j] - bf2f(h8[j]));
            }
            size_t off = (size_t)(nt * 2 + kf) * 512 + l * 8;
            *(short8*)(fh + off) = *(short8*)h8;
            *(short8*)(fl + off) = *(short8*)l8;
        }
        unsigned short* gh = (unsigned short*)(ws + WS_AOWFH);
        unsigned short* gl = (unsigned short*)(ws + WS_AOWFL);
        for (int idx = tid; idx < 4 * 2 * 64; idx += 256) {
            int nt = idx >> 7, kf = (idx >> 6) & 1, l = idx & 63;
            int row = nt * 16 + (l & 15);
            int k = kf * 32 + ((l >> 4) << 3);
            const float* src = aow + (size_t)row * DLQ + k;
            unsigned short h8[8], l8[8];
#pragma unroll
            for (int j = 0; j < 8; ++j) {
                h8[j] = f2bf(src[j]);
                l8[j] = f2bf(src[j] - bf2f(h8[j]));
            }
            size_t off = (size_t)(nt * 2 + kf) * 512 + l * 8;
            *(short8*)(gh + off) = *(short8*)h8;
            *(short8*)(gl + off) = *(short8*)l8;
        }
    }
}

// K2: pure ef GEMM (512 blocks), 64x64 tile, K split 2, BK=64, 3-term hi/lo
// bf16, single-buffered staging, XCD-rectangle swizzle (r12: FETCH 34->13 MB).
__global__ __launch_bounds__(256) void k_ef_mfma(float* __restrict__ ws) {
    __shared__ __attribute__((aligned(16))) unsigned short smem[16384];
    int tid = threadIdx.x;
    int bi = blockIdx.x;

    int xcd = bi & 7;
    int g   = bi >> 3;            // 0..63
    int kz  = g >> 5;
    int rem = g & 31;
    int nb  = (xcd >> 1) * 4 + (rem >> 3);   // 0..15
    int mb  = (xcd & 1) * 8 + (rem & 7);     // 0..15

    const unsigned short* AhP = (const unsigned short*)(ws + WS_AH);
    const unsigned short* AlP = (const unsigned short*)(ws + WS_AL);
    const unsigned short* BhP = (const unsigned short*)(ws + WS_BH);
    const unsigned short* BlP = (const unsigned short*)(ws + WS_BL);
    int w = tid >> 6, l = tid & 63;
    int wn = (w >> 1) * 32, wm = (w & 1) * 32;
    int stA = wn >> 4, stB = wm >> 4;
    f32x4 acc00 = {0.f, 0.f, 0.f, 0.f}, acc01 = acc00, acc10 = acc00, acc11 = acc00;

    for (int it = 0; it < 8; ++it) {
        int kb = kz * 8 + it;
        const char* srcs[4] = {
            (const char*)(AhP + (size_t)(nb * 16 + kb) * 4096),
            (const char*)(AlP + (size_t)(nb * 16 + kb) * 4096),
            (const char*)(BhP + (size_t)(mb * 16 + kb) * 4096),
            (const char*)(BlP + (size_t)(mb * 16 + kb) * 4096)};
#pragma unroll
        for (int p = 0; p < 4; ++p) {
#pragma unroll
            for (int h = 0; h < 2; ++h) {
                __builtin_amdgcn_global_load_lds(
                    (const __attribute__((address_space(1))) void*)(srcs[p] + h * 4096 + tid * 16),
                    (__attribute__((address_space(3))) void*)((char*)smem + p * 8192 + h * 4096 + tid * 16),
                    16, 0, 0);
            }
        }
        __syncthreads();
        const unsigned short* Ah = smem;
        const unsigned short* Al = smem + 4096;
        const unsigned short* Bh = smem + 8192;
        const unsigned short* Bl = smem + 12288;
#pragma unroll
        for (int ks = 0; ks < 2; ++ks) {
            short8 ah0 = *(const short8*)(Ah + (stA + 0) * 1024 + ks * 512 + l * 8);
            short8 ah1 = *(const short8*)(Ah + (stA + 1) * 1024 + ks * 512 + l * 8);
            short8 al0 = *(const short8*)(Al + (stA + 0) * 1024 + ks * 512 + l * 8);
            short8 al1 = *(const short8*)(Al + (stA + 1) * 1024 + ks * 512 + l * 8);
            short8 bh0 = *(const short8*)(Bh + (stB + 0) * 1024 + ks * 512 + l * 8);
            short8 bh1 = *(const short8*)(Bh + (stB + 1) * 1024 + ks * 512 + l * 8);
            short8 bl0 = *(const short8*)(Bl + (stB + 0) * 1024 + ks * 512 + l * 8);
            short8 bl1 = *(const short8*)(Bl + (stB + 1) * 1024 + ks * 512 + l * 8);
            acc00 = __builtin_amdgcn_mfma_f32_16x16x32_bf16(ah0, bh0, acc00, 0, 0, 0);
            acc00 = __builtin_amdgcn_mfma_f32_16x16x32_bf16(al0, bh0, acc00, 0, 0, 0);
            acc00 = __builtin_amdgcn_mfma_f32_16x16x32_bf16(ah0, bl0, acc00, 0, 0, 0);
            acc01 = __builtin_amdgcn_mfma_f32_16x16x32_bf16(ah0, bh1, acc01, 0, 0, 0);
            acc01 = __builtin_amdgcn_mfma_f32_16x16x32_bf16(al0, bh1, acc01, 0, 0, 0);
            acc01 = __builtin_amdgcn_mfma_f32_16x16x32_bf16(ah0, bl1, acc01, 0, 0, 0);
            acc10 = __builtin_amdgcn_mfma_f32_16x16x32_bf16(ah1, bh0, acc10, 0, 0, 0);
            acc10 = __builtin_amdgcn_mfma_f32_16x16x32_bf16(al1, bh0, acc10, 0, 0, 0);
            acc10 = __builtin_amdgcn_mfma_f32_16x16x32_bf16(ah1, bl0, acc10, 0, 0, 0);
            acc11 = __builtin_amdgcn_mfma_f32_16x16x32_bf16(ah1, bh1, acc11, 0, 0, 0);
            acc11 = __builtin_amdgcn_mfma_f32_16x16x32_bf16(al1, bh1, acc11, 0, 0, 0);
            acc11 = __builtin_amdgcn_mfma_f32_16x16x32_bf16(ah1, bl1, acc11, 0, 0, 0);
        }
        __syncthreads();
    }
    int cr = (l >> 4) * 4, cc = l & 15;
    int n0 = nb * 64, m0 = mb * 64;
    float* P = ws + (kz == 0 ? WS_EF : WS_P1);
#pragma unroll
    for (int r = 0; r < 4; ++r) {
        P[(size_t)(n0 + wn + cr + r) * DMODEL + (m0 + wm + cc)]           = acc00[r];
        P[(size_t)(n0 + wn + cr + r) * DMODEL + (m0 + wm + 16 + cc)]      = acc01[r];
        P[(size_t)(n0 + wn + 16 + cr + r) * DMODEL + (m0 + wm + cc)]      = acc10[r];
        P[(size_t)(n0 + wn + 16 + cr + r) * DMODEL + (m0 + wm + 16 + cc)] = acc11[r];
    }
}

// K3: one token per block (2 waves). MFMA qkv/attn_out, DPP reduces, ACT
// epilogue. No global atomics: lane 0 stores one packed ti int per token.
__global__ __launch_bounds__(128) void k_attn2(const float* __restrict__ pos_embed,
                                               const float* __restrict__ attn_in_b,
                                               const float* __restrict__ attn_out_b,
                                               const float* __restrict__ ln_w,
                                               const float* __restrict__ ln_b,
                                               const float* __restrict__ ls_w,
                                               const float* __restrict__ ls_b,
                                               float* __restrict__ ws) {
    int n = blockIdx.x;
    int w = threadIdx.x >> 6;
    int l = threadIdx.x & 63;
    int b = n >> 8;

    __shared__ float qkv[SEQL * 200];
    __shared__ __attribute__((aligned(16))) char ubuf[8192];   // sH/sL then ao
    __shared__ __attribute__((aligned(16))) unsigned short ctxH[1024];
    __shared__ __attribute__((aligned(16))) unsigned short ctxL[1024];
    __shared__ float lgv_sh[NE];
    unsigned short* sH = (unsigned short*)ubuf;
    unsigned short* sL = (unsigned short*)(ubuf + 4096);
    float* ao = (float*)ubuf;

    // Phase 1: seq = (P0+P1)[n] + pos (row 0 = gctx); column l in regs
    float seqc[SEQL];
    {
        const float* efp0 = ws + WS_EF + (size_t)n * DMODEL;
        const float* efp1 = ws + WS_P1 + (size_t)n * DMODEL;
        float gcv = ws[WS_GCTX + b * DLQ + l];
#pragma unroll
        for (int i = 0; i < SEQL; ++i) {
            float s = (i == 0) ? gcv
                               : efp0[(i - 1) * DLQ + l] + efp1[(i - 1) * DLQ + l] +
                                 pos_embed[(i - 1) * DLQ + l];
            seqc[i] = s;
            int lo_r = w * 9, hi_r = w * 9 + 8;
            if (i >= lo_r && i <= hi_r && i < SEQL) {
                unsigned short hs = f2bf(s);
                unsigned short lsv = f2bf(s - bf2f(hs));
                int mt = i >> 4;
                int ls = (i & 15) + (((l >> 3) & 3) << 4);
                int kf = l >> 5;
                int j = l & 7;
                size_t off = (size_t)(mt * 2 + kf) * 512 + ls * 8 + j;
                sH[off] = hs;
                sL[off] = lsv;
            }
        }
    }
    __syncthreads();

    // Phase 2: qkv = seq @ aiw^T via MFMA (wave w: N-tiles w*6..w*6+5)
    {
        const unsigned short* fh = (const unsigned short*)(ws + WS_AIWFH);
        const unsigned short* fl = (const unsigned short*)(ws + WS_AIWFL);
        f32x4 acc[6][2];
#pragma unroll
        for (int t = 0; t < 6; ++t)
#pragma unroll
            for (int m = 0; m < 2; ++m) acc[t][m] = (f32x4){0.f, 0.f, 0.f, 0.f};
#pragma unroll
        for (int kf = 0; kf < 2; ++kf) {
            short8 ah0 = *(const short8*)(sH + (0 * 2 + kf) * 512 + l * 8);
            short8 ah1 = *(const short8*)(sH + (1 * 2 + kf) * 512 + l * 8);
            short8 al0 = *(const short8*)(sL + (0 * 2 + kf) * 512 + l * 8);
            short8 al1 = *(const short8*)(sL + (1 * 2 + kf) * 512 + l * 8);
#pragma unroll
            for (int t = 0; t < 6; ++t) {
                int nt = w * 6 + t;
                short8 bh = *(const short8*)(fh + (size_t)(nt * 2 + kf) * 512 + l * 8);
                short8 bl = *(const short8*)(fl + (size_t)(nt * 2 + kf) * 512 + l * 8);
                acc[t][0] = __builtin_amdgcn_mfma_f32_16x16x32_bf16(ah0, bh, acc[t][0], 0, 0, 0);
                acc[t][0] = __builtin_amdgcn_mfma_f32_16x16x32_bf16(al0, bh, acc[t][0], 0, 0, 0);
                acc[t][0] = __builtin_amdgcn_mfma_f32_16x16x32_bf16(ah0, bl, acc[t][0], 0, 0, 0);
                acc[t][1] = __builtin_amdgcn_mfma_f32_16x16x32_bf16(ah1, bh, acc[t][1], 0, 0, 0);
                acc[t][1] = __builtin_amdgcn_mfma_f32_16x16x32_bf16(al1, bh, acc[t][1], 0, 0, 0);
                acc[t][1] = __builtin_amdgcn_mfma_f32_16x16x32_bf16(ah1, bl, acc[t][1], 0, 0, 0);
            }
        }
#pragma unroll
        for (int t = 0; t < 6; ++t) {
            int col = (w * 6 + t) * 16 + (l & 15);
            float bias = attn_in_b[col];
#pragma unroll
            for (int r = 0; r < 4; ++r) {
                int row = (l >> 4) * 4 + r;
                qkv[row * 200 + col] = acc[t][0][r] + bias;
            }
            if ((l >> 4) == 0) qkv[16 * 200 + col] = acc[t][1][0] + bias;
        }
    }
    __syncthreads();

    // Phase 3: scores via DPP 16-lane reduce, lane-local softmax, ctx.
    {
        int g = l >> 4;
        float kc[SEQL], vc[SEQL];
#pragma unroll
        for (int j = 0; j < SEQL; ++j) {
            kc[j] = qkv[j * 200 + 64 + g * 16 + (l & 15)];
            vc[j] = qkv[j * 200 + 128 + l];
        }
        for (int i = w * 8 + 1; i <= w * 8 + 8; ++i) {
            float qi = qkv[i * 200 + g * 16 + (l & 15)];
            float sj[SEQL];
#pragma unroll
            for (int j = 0; j < SEQL; ++j) {
                sj[j] = rsum16(qi * kc[j]) * 0.25f;
            }
            float m = sj[0];
#pragma unroll
            for (int j = 1; j < SEQL; ++j) m = fmaxf(m, sj[j]);
            float ssum = 0.f;
#pragma unroll
            for (int j = 0; j < SEQL; ++j) { sj[j] = __expf(sj[j] - m); ssum += sj[j]; }
            float inv = 1.f / ssum;
            float c = 0.f;
#pragma unroll
            for (int j = 0; j < SEQL; ++j) c += sj[j] * vc[j];
            c *= inv;
            unsigned short ch = f2bf(c);
            unsigned short cl = f2bf(c - bf2f(ch));
            int ls = ((i - 1) & 15) + (((l >> 3) & 3) << 4);
            int kf = l >> 5;
            int j2 = l & 7;
            size_t off = (size_t)kf * 512 + ls * 8 + j2;
            ctxH[off] = ch;
            ctxL[off] = cl;
        }
    }
    __syncthreads();

    // Phase 4: attn_out = ctx @ aow^T via MFMA (ao overlays sH/sL region)
    {
        const unsigned short* gh = (const unsigned short*)(ws + WS_AOWFH);
        const unsigned short* gl = (const unsigned short*)(ws + WS_AOWFL);
        f32x4 acc[2];
        acc[0] = (f32x4){0.f, 0.f, 0.f, 0.f};
        acc[1] = acc[0];
#pragma unroll
        for (int kf = 0; kf < 2; ++kf) {
            short8 ah = *(const short8*)(ctxH + kf * 512 + l * 8);
            short8 al = *(const short8*)(ctxL + kf * 512 + l * 8);
#pragma unroll
            for (int t = 0; t < 2; ++t) {
                int nt = w * 2 + t;
                short8 bh = *(const short8*)(gh + (size_t)(nt * 2 + kf) * 512 + l * 8);
                short8 bl = *(const short8*)(gl + (size_t)(nt * 2 + kf) * 512 + l * 8);
                acc[t] = __builtin_amdgcn_mfma_f32_16x16x32_bf16(ah, bh, acc[t], 0, 0, 0);
                acc[t] = __builtin_amdgcn_mfma_f32_16x16x32_bf16(al, bh, acc[t], 0, 0, 0);
                acc[t] = __builtin_amdgcn_mfma_f32_16x16x32_bf16(ah, bl, acc[t], 0, 0, 0);
            }
        }
        __syncthreads();
#pragma unroll
        for (int t = 0; t < 2; ++t) {
            int col = (w * 2 + t) * 16 + (l & 15);
            float bias = attn_out_b[col];
#pragma unroll
            for (int r = 0; r < 4; ++r) {
                int row = (l >> 4) * 4 + r;
                ao[row * 72 + col] = acc[t][r] + bias;
            }
        }
    }
    __syncthreads();

    // Phase 5: residual + LN + logits (wave w: e = w*8..w*8+7)
    float rs[SEQL];
#pragma unroll
    for (int i = 1; i < SEQL; ++i) rs[i] = seqc[i] + ao[(i - 1) * 72 + l];

    float c1 = ln_w[l] * ls_w[l];
    float c1sum = rsum64(c1);
    float c0sum = rsum64(ln_b[l] * ls_w[l]);
    float lsb0 = ls_b[0];
#pragma unroll
    for (int ee = 0; ee < 8; ++ee) {
        int e = w * 8 + ee;
        float x = rs[e + 1];
        float s1 = rsum64(x);
        float s2 = rsum64(x * x);
        float s3 = rsum64(x * c1);
        float mu = s1 * (1.0f / DLQ);
        float var = s2 * (1.0f / DLQ) - mu * mu;
        float rstd = rsqrtf(var + 1e-5f);
        float lgv = rstd * (s3 - mu * c1sum) + c0sum + lsb0 + ws[WS_GB + b * NE + e];
        if (l == 0) lgv_sh[e] = lgv;
    }
    __syncthreads();

    // softmax + top2 (only wave 0 commits)
    if (w == 0) {
        float p[NE];
        float lgv[NE];
#pragma unroll
        for (int e = 0; e < NE; ++e) lgv[e] = lgv_sh[e];
        float m = lgv[0];
#pragma unroll
        for (int e = 1; e < NE; ++e) m = fmaxf(m, lgv[e]);
        float ssum = 0.f;
#pragma unroll
        for (int e = 0; e < NE; ++e) { p[e] = __expf(lgv[e] - m); ssum += p[e]; }
        float inv = 1.f / ssum;
#pragma unroll
        for (int e = 0; e < NE; ++e) p[e] *= inv;
        int t0 = 0; float b0 = p[0];
#pragma unroll
        for (int e = 1; e < NE; ++e) if (p[e] > b0) { b0 = p[e]; t0 = e; }
        int t1 = -1; float b1 = -1.f;
#pragma unroll
        for (int e = 0; e < NE; ++e) if (e != t0 && p[e] > b1) { b1 = p[e]; t1 = e; }

        float sw = b0 + b1;
        float tw0 = b0 / sw, tw1 = b1 / sw;
        // ACT epilogue: gelu(ef of selected experts) * weight, bf16
        unsigned short* actp = (unsigned short*)(ws + WS_ACT);
        float efv0 = ws[WS_EF + (size_t)n * DMODEL + t0 * DLQ + l] +
                     ws[WS_P1 + (size_t)n * DMODEL + t0 * DLQ + l];
        float efv1 = ws[WS_EF + (size_t)n * DMODEL + t1 * DLQ + l] +
                     ws[WS_P1 + (size_t)n * DMODEL + t1 * DLQ + l];
        actp[(size_t)(n * 2 + 0) * 64 + l] = f2bf(gelu_exact(efv0) * tw0);
        actp[(size_t)(n * 2 + 1) * 64 + l] = f2bf(gelu_exact(efv1) * tw1);
        if (l == 0) {
#pragma unroll
            for (int e = 0; e < NE; ++e) ws[WS_PR + (size_t)n * NE + e] = p[e];
            ((int*)(ws + WS_TI))[n] = t0 | (t1 << 8);
        }
    }
}

// K4 (fused): blocks (e<16, ct): expert-major MoE GEMM. B-frags converted
// inline from fp32 w_up (w_up read exactly once, coalesced in 16-lane groups).
// Ballot-compacted local token list, MFMA, atomicAdd into memset-zeroed out.
// Block (16, 0): aux loss.
__global__ __launch_bounds__(256) void k_moe_gemm(const float* __restrict__ w_up,
                                                  float* __restrict__ ws,
                                                  float* __restrict__ out) {
    __shared__ int lst[2048];
    __shared__ int lcnt;
    __shared__ float wsum[4][NE];
    __shared__ int hist[NE];
    int tid = threadIdx.x;
    int wv = tid >> 6, l = tid & 63;

    if (blockIdx.x == NE) {
        if (blockIdx.y != 0) return;
        if (tid < NE) hist[tid] = 0;
        __syncthreads();
        {
            const int* tip = (const int*)(ws + WS_TI);
#pragma unroll
            for (int c = 0; c < 4; ++c) {
                int pk = tip[tid * 4 + c];
                atomicAdd(&hist[pk & 0xff], 1);
                atomicAdd(&hist[(pk >> 8) & 0xff], 1);
            }
        }
        float p[NE];
#pragma unroll
        for (int e = 0; e < NE; ++e) p[e] = 0.f;
        const float* pr = ws + WS_PR + (size_t)tid * 64;
#pragma unroll
        for (int r = 0; r < 4; ++r)
#pragma unroll
            for (int q = 0; q < 4; ++q) {
                float4 v = *(const float4*)(pr + r * 16 + q * 4);
                p[q * 4 + 0] += v.x; p[q * 4 + 1] += v.y;
                p[q * 4 + 2] += v.z; p[q * 4 + 3] += v.w;
            }
#pragma unroll
        for (int e = 0; e < NE; ++e) p[e] = rsum64(p[e]);
        if (l == 0) {
#pragma unroll
            for (int e = 0; e < NE; ++e) wsum[wv][e] = p[e];
        }
        __syncthreads();
        if (tid == 0) {
            float s = 0.f;
#pragma unroll
            for (int e = 0; e < NE; ++e) {
                float sp = wsum[0][e] + wsum[1][e] + wsum[2][e] + wsum[3][e];
                s += sp * (float)hist[e];
            }
            out[(size_t)NTOK * DMODEL] = (float)NE * s / ((float)NTOK * (float)NTOK);
        }
        return;
    }

    // ---- MoE GEMM ----
    int e = blockIdx.x, ct = blockIdx.y;
    if (tid == 0) lcnt = 0;
    __syncthreads();
    {
        const int* tip = (const int*)(ws + WS_TI);
#pragma unroll
        for (int c = 0; c < 4; ++c) {
            int tok = wv * 256 + c * 64 + l;
            int pk = tip[tok];
            bool m1 = ((pk >> 8) & 0xff) == e;
            bool m = ((pk & 0xff) == e) || m1;
            unsigned long long mask = __ballot(m);
            int base = 0;
            if (l == 0 && mask) base = atomicAdd(&lcnt, __popcll(mask));
            base = __shfl(base, 0);
            if (m) {
                int pos = base + __popcll(mask & ((1ull << l) - 1ull));
                lst[pos] = tok * 2 + (m1 ? 1 : 0);
            }
        }
    }
    __syncthreads();
    int cnt = lcnt;
    if (cnt == 0) return;

    // Inline B-frag conversion: lane needs w_up[e][kb+j][col], j=0..7 (+32)
    int col = ct * 64 + wv * 16 + (l & 15);
    int kb = (l >> 4) * 8;
    const float* wue = w_up + (size_t)e * DLQ * DMODEL + col;
    unsigned short b0v[8], b1v[8];
#pragma unroll
    for (int j = 0; j < 8; ++j) {
        b0v[j] = f2bf(wue[(size_t)(kb + j) * DMODEL]);
        b1v[j] = f2bf(wue[(size_t)(kb + 32 + j) * DMODEL]);
    }
    short8 bf0 = *(short8*)b0v;
    short8 bf1 = *(short8*)b1v;

    const unsigned short* actp = (const unsigned short*)(ws + WS_ACT);
    int cr = (l >> 4) * 4;

    for (int mt = 0; mt < cnt; mt += 16) {
        int row = mt + (l & 15);
        short8 a0 = {0, 0, 0, 0, 0, 0, 0, 0};
        short8 a1 = {0, 0, 0, 0, 0, 0, 0, 0};
        if (row < cnt) {
            int pk = lst[row];
            a0 = *(const short8*)(actp + (size_t)pk * 64 + kb);
            a1 = *(const short8*)(actp + (size_t)pk * 64 + 32 + kb);
        }
        f32x4 acc = {0.f, 0.f, 0.f, 0.f};
        acc = __builtin_amdgcn_mfma_f32_16x16x32_bf16(a0, bf0, acc, 0, 0, 0);
        acc = __builtin_amdgcn_mfma_f32_16x16x32_bf16(a1, bf1, acc, 0, 0, 0);
#pragma unroll
        for (int r = 0; r < 4; ++r) {
            int rr = mt + cr + r;
            if (rr < cnt) {
                int pk = lst[rr];
                atomicAdd(&out[(size_t)(pk >> 1) * DMODEL + col], acc[r]);
            }
        }
    }
}

extern "C" void kernel_launch(void* const* d_in, const int* in_sizes, int n_in,
                              void* d_out, int out_size, void* d_ws, size_t ws_size,
                              hipStream_t stream) {
    const float* x          = (const float*)d_in[0];
    const float* w_down     = (const float*)d_in[1];
    const float* pos_embed  = (const float*)d_in[2];
    const float* gp_w       = (const float*)d_in[3];
    const float* gp_b       = (const float*)d_in[4];
    const float* attn_in_w  = (const float*)d_in[5];
    const float* attn_in_b  = (const float*)d_in[6];
    const float* attn_out_w = (const float*)d_in[7];
    const float* attn_out_b = (const float*)d_in[8];
    const float* ln_w       = (const float*)d_in[9];
    const float* ln_b       = (const float*)d_in[10];
    const float* ls_w       = (const float*)d_in[11];
    const float* ls_b       = (const float*)d_in[12];
    const float* g1_w       = (const float*)d_in[13];
    const float* g1_b       = (const float*)d_in[14];
    const float* g2_w       = (const float*)d_in[15];
    const float* g2_b       = (const float*)d_in[16];
    const float* w_up       = (const float*)d_in[17];
    float* ws  = (float*)d_ws;
    float* out = (float*)d_out;

    hipMemsetAsync(out, 0, (size_t)out_size * sizeof(float), stream);
    k_prep<<<1029, 256, 0, stream>>>(x, w_down, attn_in_w, attn_out_w,
                                     gp_w, gp_b, g1_w, g1_b, g2_w, g2_b, ws);
    k_ef_mfma<<<512, 256, 0, stream>>>(ws);
    k_attn2<<<NTOK, 128, 0, stream>>>(pos_embed, attn_in_b, attn_out_b,
                                      ln_w, ln_b, ls_w, ls_b, ws);
    k_moe_gemm<<<dim3(NE + 1, 16), 256, 0, stream>>>(w_up, ws, out);
}

// Round 14
// 165.929 us; speedup vs baseline: 1.1137x; 1.1137x over previous
//
#include <hip/hip_runtime.h>
#include <math.h>

// Problem constants
#define NB 4
#define TT 256
#define DMODEL 1024
#define NE 16
#define DLQ 64
#define NH 4
#define HD 16
#define SEQL 17
#define NTOK 1024   // NB*TT

// Workspace layout (float offsets). ws is ~268 MB; regions are private.
static constexpr size_t WS_EF    = 0;          // 1024x1024 fp32 ef partial P0
static constexpr size_t WS_AH    = 1048576;    // x hi bf16 plane, frag-swizzled
static constexpr size_t WS_AL    = 1572864;    // x lo
static constexpr size_t WS_BH    = 2097152;    // w_down hi
static constexpr size_t WS_BL    = 2621440;    // w_down lo
static constexpr size_t WS_P1    = 3145728;    // K-split partial P1
static constexpr size_t WS_ACT   = 4194304;    // act bf16 [2048][64]
static constexpr size_t WS_AIWFH = 4259840;    // attn_in_w hi frags (12288 sh)
static constexpr size_t WS_AIWFL = 4265984;    // attn_in_w lo frags
static constexpr size_t WS_AOWFH = 4272128;    // attn_out_w hi frags (4096 sh)
static constexpr size_t WS_AOWFL = 4274176;    // attn_out_w lo frags
static constexpr size_t WS_PR    = 4308992;    // 1024x16 probs
static constexpr size_t WS_TI    = 4325376;    // 1024 packed ints: t0 | t1<<8
static constexpr size_t WS_GCTX  = 4326400;    // 4x64
static constexpr size_t WS_GB    = 4326656;    // 4x16
static constexpr size_t WS_GPH   = 4400128;    // gp_w hi frag plane (64K sh)
static constexpr size_t WS_GPL   = 4432896;    // gp_w lo frag plane
static constexpr size_t WS_GPX0  = 4465664;    // gp_x partial kz=0 [1024][64]
static constexpr size_t WS_GPX1  = 4531200;    // gp_x partial kz=1

typedef __attribute__((ext_vector_type(8))) short short8;
typedef __attribute__((ext_vector_type(4))) float f32x4;

__device__ __forceinline__ float gelu_exact(float x) {
    return 0.5f * x * (1.0f + erff(x * 0.70710678118654752f));
}

__device__ __forceinline__ unsigned short f2bf(float f) {
    unsigned int u = __float_as_uint(f);
    unsigned int r = (u + 0x7fffu + ((u >> 16) & 1u)) >> 16;
    return (unsigned short)r;
}
__device__ __forceinline__ float bf2f(unsigned short h) {
    return __uint_as_float(((unsigned int)h) << 16);
}

// DPP row_ror all-reduce within 16-lane rows: VALU pipe, zero LDS ops.
#define DPP_ADD(v, ctrl) { int _m = __builtin_amdgcn_update_dpp(0, __float_as_int(v), ctrl, 0xF, 0xF, true); \
                           v += __int_as_float(_m); }
__device__ __forceinline__ float rsum16(float v) {
    DPP_ADD(v, 0x128);  // row_ror:8
    DPP_ADD(v, 0x124);  // row_ror:4
    DPP_ADD(v, 0x122);  // row_ror:2
    DPP_ADD(v, 0x121);  // row_ror:1
    return v;
}
__device__ __forceinline__ float rsum64(float v) {
    v = rsum16(v);
    v += __shfl_xor(v, 16);
    v += __shfl_xor(v, 32);
    return v;
}

// K0 (fused): blocks 0..1023: x / w_down hi/lo bf16 frag-swizzled planes;
// blocks 1024..1055: gp_w hi/lo frag plane (one 64-row B tile);
// block 1056: attn weight frag planes. NO serial gctx blocks anymore —
// the gp projection rides the MFMA GEMM (r13 post-mortem: 3 rounds showed
// the 4-block matvec tail is structural, ~40-50 us wherever it lives).
__global__ __launch_bounds__(256) void k_prep(const float* __restrict__ x,
                                              const float* __restrict__ wdn,
                                              const float* __restrict__ gp_w,
                                              const float* __restrict__ aiw,
                                              const float* __restrict__ aow,
                                              float* __restrict__ ws) {
    int bi = blockIdx.x;
    int tid = threadIdx.x;
    if (bi < 1024) {
        int which = bi >> 9;   // 0: x, 1: w_down
        int t = (bi & 511) * 256 + tid;
        int row = t >> 7;
        int col0 = (t & 127) * 8;
        const float* src = which ? wdn : x;
        unsigned short* hp = (unsigned short*)(ws + (which ? WS_BH : WS_AH));
        unsigned short* lp = (unsigned short*)(ws + (which ? WS_BL : WS_AL));
        float4 v0 = *(const float4*)(src + (size_t)row * DMODEL + col0);
        float4 v1 = *(const float4*)(src + (size_t)row * DMODEL + col0 + 4);
        float vv[8] = {v0.x, v0.y, v0.z, v0.w, v1.x, v1.y, v1.z, v1.w};
        unsigned short h8[8], l8[8];
#pragma unroll
        for (int j = 0; j < 8; ++j) {
            h8[j] = f2bf(vv[j]);
            l8[j] = f2bf(vv[j] - bf2f(h8[j]));
        }
        int nb = row >> 6, kb = col0 >> 6;
        int st = (row & 63) >> 4;
        int ks = (col0 & 63) >> 5;
        int ln = (row & 15) + (((col0 >> 3) & 3) << 4);
        size_t off = (size_t)(nb * 16 + kb) * 4096 + st * 1024 + ks * 512 + ln * 8;
        *(short8*)(hp + off) = *(short8*)h8;
        *(short8*)(lp + off) = *(short8*)l8;
    } else if (bi < 1056) {
        // gp_w: 64 rows x 1024 cols -> one frag-swizzled B tile (nb=0)
        int t = (bi - 1024) * 256 + tid;   // 0..8191
        int row = t >> 7;                  // 0..63
        int col0 = (t & 127) * 8;
        unsigned short* hp = (unsigned short*)(ws + WS_GPH);
        unsigned short* lp = (unsigned short*)(ws + WS_GPL);
        float4 v0 = *(const float4*)(gp_w + (size_t)row * DMODEL + col0);
        float4 v1 = *(const float4*)(gp_w + (size_t)row * DMODEL + col0 + 4);
        float vv[8] = {v0.x, v0.y, v0.z, v0.w, v1.x, v1.y, v1.z, v1.w};
        unsigned short h8[8], l8[8];
#pragma unroll
        for (int j = 0; j < 8; ++j) {
            h8[j] = f2bf(vv[j]);
            l8[j] = f2bf(vv[j] - bf2f(h8[j]));
        }
        int kb = col0 >> 6;
        int st = row >> 4;
        int ks = (col0 & 63) >> 5;
        int ln = (row & 15) + (((col0 >> 3) & 3) << 4);
        size_t off = (size_t)kb * 4096 + st * 1024 + ks * 512 + ln * 8;
        *(short8*)(hp + off) = *(short8*)h8;
        *(short8*)(lp + off) = *(short8*)l8;
    } else {
        unsigned short* fh = (unsigned short*)(ws + WS_AIWFH);
        unsigned short* fl = (unsigned short*)(ws + WS_AIWFL);
        for (int idx = tid; idx < 12 * 2 * 64; idx += 256) {
            int nt = idx >> 7, kf = (idx >> 6) & 1, l = idx & 63;
            int row = nt * 16 + (l & 15);
            int k = kf * 32 + ((l >> 4) << 3);
            const float* src = aiw + (size_t)row * DLQ + k;
            unsigned short h8[8], l8[8];
#pragma unroll
            for (int j = 0; j < 8; ++j) {
                h8[j] = f2bf(src[j]);
                l8[j] = f2bf(src[j] - bf2f(h8[j]));
            }
            size_t off = (size_t)(nt * 2 + kf) * 512 + l * 8;
            *(short8*)(fh + off) = *(short8*)h8;
            *(short8*)(fl + off) = *(short8*)l8;
        }
        unsigned short* gh = (unsigned short*)(ws + WS_AOWFH);
        unsigned short* gl = (unsigned short*)(ws + WS_AOWFL);
        for (int idx = tid; idx < 4 * 2 * 64; idx += 256) {
            int nt = idx >> 7, kf = (idx >> 6) & 1, l = idx & 63;
            int row = nt * 16 + (l & 15);
            int k = kf * 32 + ((l >> 4) << 3);
            const float* src = aow + (size_t)row * DLQ + k;
            unsigned short h8[8], l8[8];
#pragma unroll
            for (int j = 0; j < 8; ++j) {
                h8[j] = f2bf(src[j]);
                l8[j] = f2bf(src[j] - bf2f(h8[j]));
            }
            size_t off = (size_t)(nt * 2 + kf) * 512 + l * 8;
            *(short8*)(gh + off) = *(short8*)h8;
            *(short8*)(gl + off) = *(short8*)l8;
        }
    }
}

// K2: ef GEMM + gp projection. Blocks 0..511: ef (XCD-rectangle swizzle,
// r12-validated FETCH 34->13 MB). Blocks 512..543: gp_x = x @ gp_w^T
// (nb 0..15, kz 0..1, single 64-col B tile from WS_GPH/GPL) -> WS_GPX0/1.
__global__ __launch_bounds__(256) void k_ef_mfma(float* __restrict__ ws) {
    __shared__ __attribute__((aligned(16))) unsigned short smem[16384];
    int tid = threadIdx.x;
    int bi = blockIdx.x;

    int nb, mb, kz;
    bool gp = bi >= 512;
    if (gp) {
        int idx = bi - 512;
        nb = idx & 15;
        kz = idx >> 4;
        mb = 0;
    } else {
        int xcd = bi & 7;
        int g   = bi >> 3;
        kz  = g >> 5;
        int rem = g & 31;
        nb  = (xcd >> 1) * 4 + (rem >> 3);
        mb  = (xcd & 1) * 8 + (rem & 7);
    }

    const unsigned short* AhP = (const unsigned short*)(ws + WS_AH);
    const unsigned short* AlP = (const unsigned short*)(ws + WS_AL);
    const unsigned short* BhP = gp ? (const unsigned short*)(ws + WS_GPH)
                                   : (const unsigned short*)(ws + WS_BH);
    const unsigned short* BlP = gp ? (const unsigned short*)(ws + WS_GPL)
                                   : (const unsigned short*)(ws + WS_BL);
    int w = tid >> 6, l = tid & 63;
    int wn = (w >> 1) * 32, wm = (w & 1) * 32;
    int stA = wn >> 4, stB = wm >> 4;
    f32x4 acc00 = {0.f, 0.f, 0.f, 0.f}, acc01 = acc00, acc10 = acc00, acc11 = acc00;

    for (int it = 0; it < 8; ++it) {
        int kb = kz * 8 + it;
        const char* srcs[4] = {
            (const char*)(AhP + (size_t)(nb * 16 + kb) * 4096),
            (const char*)(AlP + (size_t)(nb * 16 + kb) * 4096),
            (const char*)(BhP + (size_t)(mb * 16 + kb) * 4096),
            (const char*)(BlP + (size_t)(mb * 16 + kb) * 4096)};
#pragma unroll
        for (int p = 0; p < 4; ++p) {
#pragma unroll
            for (int h = 0; h < 2; ++h) {
                __builtin_amdgcn_global_load_lds(
                    (const __attribute__((address_space(1))) void*)(srcs[p] + h * 4096 + tid * 16),
                    (__attribute__((address_space(3))) void*)((char*)smem + p * 8192 + h * 4096 + tid * 16),
                    16, 0, 0);
            }
        }
        __syncthreads();
        const unsigned short* Ah = smem;
        const unsigned short* Al = smem + 4096;
        const unsigned short* Bh = smem + 8192;
        const unsigned short* Bl = smem + 12288;
#pragma unroll
        for (int ks = 0; ks < 2; ++ks) {
            short8 ah0 = *(const short8*)(Ah + (stA + 0) * 1024 + ks * 512 + l * 8);
            short8 ah1 = *(const short8*)(Ah + (stA + 1) * 1024 + ks * 512 + l * 8);
            short8 al0 = *(const short8*)(Al + (stA + 0) * 1024 + ks * 512 + l * 8);
            short8 al1 = *(const short8*)(Al + (stA + 1) * 1024 + ks * 512 + l * 8);
            short8 bh0 = *(const short8*)(Bh + (stB + 0) * 1024 + ks * 512 + l * 8);
            short8 bh1 = *(const short8*)(Bh + (stB + 1) * 1024 + ks * 512 + l * 8);
            short8 bl0 = *(const short8*)(Bl + (stB + 0) * 1024 + ks * 512 + l * 8);
            short8 bl1 = *(const short8*)(Bl + (stB + 1) * 1024 + ks * 512 + l * 8);
            acc00 = __builtin_amdgcn_mfma_f32_16x16x32_bf16(ah0, bh0, acc00, 0, 0, 0);
            acc00 = __builtin_amdgcn_mfma_f32_16x16x32_bf16(al0, bh0, acc00, 0, 0, 0);
            acc00 = __builtin_amdgcn_mfma_f32_16x16x32_bf16(ah0, bl0, acc00, 0, 0, 0);
            acc01 = __builtin_amdgcn_mfma_f32_16x16x32_bf16(ah0, bh1, acc01, 0, 0, 0);
            acc01 = __builtin_amdgcn_mfma_f32_16x16x32_bf16(al0, bh1, acc01, 0, 0, 0);
            acc01 = __builtin_amdgcn_mfma_f32_16x16x32_bf16(ah0, bl1, acc01, 0, 0, 0);
            acc10 = __builtin_amdgcn_mfma_f32_16x16x32_bf16(ah1, bh0, acc10, 0, 0, 0);
            acc10 = __builtin_amdgcn_mfma_f32_16x16x32_bf16(al1, bh0, acc10, 0, 0, 0);
            acc10 = __builtin_amdgcn_mfma_f32_16x16x32_bf16(ah1, bl0, acc10, 0, 0, 0);
            acc11 = __builtin_amdgcn_mfma_f32_16x16x32_bf16(ah1, bh1, acc11, 0, 0, 0);
            acc11 = __builtin_amdgcn_mfma_f32_16x16x32_bf16(al1, bh1, acc11, 0, 0, 0);
            acc11 = __builtin_amdgcn_mfma_f32_16x16x32_bf16(ah1, bl1, acc11, 0, 0, 0);
        }
        __syncthreads();
    }
    int cr = (l >> 4) * 4, cc = l & 15;
    int n0 = nb * 64;
    float* P;
    size_t rstride;
    int m0;
    if (gp) {
        P = ws + (kz == 0 ? WS_GPX0 : WS_GPX1);
        rstride = 64;
        m0 = 0;
    } else {
        P = ws + (kz == 0 ? WS_EF : WS_P1);
        rstride = DMODEL;
        m0 = mb * 64;
    }
#pragma unroll
    for (int r = 0; r < 4; ++r) {
        P[(size_t)(n0 + wn + cr + r) * rstride + (m0 + wm + cc)]           = acc00[r];
        P[(size_t)(n0 + wn + cr + r) * rstride + (m0 + wm + 16 + cc)]      = acc01[r];
        P[(size_t)(n0 + wn + 16 + cr + r) * rstride + (m0 + wm + cc)]      = acc10[r];
        P[(size_t)(n0 + wn + 16 + cr + r) * rstride + (m0 + wm + 16 + cc)] = acc11[r];
    }
}

// K2b: per-batch gctx (column-sum of L2-hot gp_x, coalesced) + g1/g2 MLP.
__global__ __launch_bounds__(256) void k_gctx(const float* __restrict__ gp_b,
                                              const float* __restrict__ g1_w,
                                              const float* __restrict__ g1_b,
                                              const float* __restrict__ g2_w,
                                              const float* __restrict__ g2_b,
                                              float* __restrict__ ws) {
    __shared__ float part[4][DLQ];
    __shared__ float gc[DLQ];
    __shared__ float gb1[128];
    int b = blockIdx.x;
    int tid = threadIdx.x;
    int wv = tid >> 6, l = tid & 63;
    // column sums over 256 tokens: wave wv handles 64 rows (coalesced 256B/row)
    {
        const float* g0 = ws + WS_GPX0 + (size_t)(b * 256 + wv * 64) * 64 + l;
        const float* g1p = ws + WS_GPX1 + (size_t)(b * 256 + wv * 64) * 64 + l;
        float s = 0.f;
#pragma unroll 8
        for (int t = 0; t < 64; ++t) s += g0[t * 64] + g1p[t * 64];
        part[wv][l] = s;
    }
    __syncthreads();
    if (wv == 0) {
        float v = (part[0][l] + part[1][l] + part[2][l] + part[3][l]) * (1.0f / TT) + gp_b[l];
        gc[l] = v;
        ws[WS_GCTX + b * DLQ + l] = v;
    }
    __syncthreads();
    // g1: wave wv rows wv*32..+31 in groups of 4 (ILP)
    {
        float gcl = gc[l];
        for (int rq = 0; rq < 8; ++rq) {
            int o = wv * 32 + rq * 4;
            float s[4];
#pragma unroll
            for (int r = 0; r < 4; ++r) s[r] = gcl * g1_w[(size_t)(o + r) * DLQ + l];
#pragma unroll
            for (int r = 0; r < 4; ++r) s[r] = rsum64(s[r]);
            if (l == 0) {
#pragma unroll
                for (int r = 0; r < 4; ++r) gb1[o + r] = gelu_exact(s[r] + g1_b[o + r]);
            }
        }
    }
    __syncthreads();
    // g2: wave wv rows wv*4..+3
    {
        float v0 = gb1[l * 2], v1 = gb1[l * 2 + 1];
        int o = wv * 4;
        float s[4];
#pragma unroll
        for (int r = 0; r < 4; ++r)
            s[r] = v0 * g2_w[(size_t)(o + r) * 128 + l * 2] +
                   v1 * g2_w[(size_t)(o + r) * 128 + l * 2 + 1];
#pragma unroll
        for (int r = 0; r < 4; ++r) s[r] = rsum64(s[r]);
        if (l == 0) {
#pragma unroll
            for (int r = 0; r < 4; ++r) ws[WS_GB + b * NE + o + r] = s[r] + g2_b[o + r];
        }
    }
}

// K3: one token per block (2 waves). MFMA qkv/attn_out, DPP reduces, ACT
// epilogue. No global atomics: lane 0 stores one packed ti int per token.
__global__ __launch_bounds__(128) void k_attn2(const float* __restrict__ pos_embed,
                                               const float* __restrict__ attn_in_b,
                                               const float* __restrict__ attn_out_b,
                                               const float* __restrict__ ln_w,
                                               const float* __restrict__ ln_b,
                                               const float* __restrict__ ls_w,
                                               const float* __restrict__ ls_b,
                                               float* __restrict__ ws) {
    int n = blockIdx.x;
    int w = threadIdx.x >> 6;
    int l = threadIdx.x & 63;
    int b = n >> 8;

    __shared__ float qkv[SEQL * 200];
    __shared__ __attribute__((aligned(16))) char ubuf[8192];   // sH/sL then ao
    __shared__ __attribute__((aligned(16))) unsigned short ctxH[1024];
    __shared__ __attribute__((aligned(16))) unsigned short ctxL[1024];
    __shared__ float lgv_sh[NE];
    unsigned short* sH = (unsigned short*)ubuf;
    unsigned short* sL = (unsigned short*)(ubuf + 4096);
    float* ao = (float*)ubuf;

    // Phase 1: seq = (P0+P1)[n] + pos (row 0 = gctx); column l in regs
    float seqc[SEQL];
    {
        const float* efp0 = ws + WS_EF + (size_t)n * DMODEL;
        const float* efp1 = ws + WS_P1 + (size_t)n * DMODEL;
        float gcv = ws[WS_GCTX + b * DLQ + l];
#pragma unroll
        for (int i = 0; i < SEQL; ++i) {
            float s = (i == 0) ? gcv
                               : efp0[(i - 1) * DLQ + l] + efp1[(i - 1) * DLQ + l] +
                                 pos_embed[(i - 1) * DLQ + l];
            seqc[i] = s;
            int lo_r = w * 9, hi_r = w * 9 + 8;
            if (i >= lo_r && i <= hi_r && i < SEQL) {
                unsigned short hs = f2bf(s);
                unsigned short lsv = f2bf(s - bf2f(hs));
                int mt = i >> 4;
                int ls = (i & 15) + (((l >> 3) & 3) << 4);
                int kf = l >> 5;
                int j = l & 7;
                size_t off = (size_t)(mt * 2 + kf) * 512 + ls * 8 + j;
                sH[off] = hs;
                sL[off] = lsv;
            }
        }
    }
    __syncthreads();

    // Phase 2: qkv = seq @ aiw^T via MFMA (wave w: N-tiles w*6..w*6+5)
    {
        const unsigned short* fh = (const unsigned short*)(ws + WS_AIWFH);
        const unsigned short* fl = (const unsigned short*)(ws + WS_AIWFL);
        f32x4 acc[6][2];
#pragma unroll
        for (int t = 0; t < 6; ++t)
#pragma unroll
            for (int m = 0; m < 2; ++m) acc[t][m] = (f32x4){0.f, 0.f, 0.f, 0.f};
#pragma unroll
        for (int kf = 0; kf < 2; ++kf) {
            short8 ah0 = *(const short8*)(sH + (0 * 2 + kf) * 512 + l * 8);
            short8 ah1 = *(const short8*)(sH + (1 * 2 + kf) * 512 + l * 8);
            short8 al0 = *(const short8*)(sL + (0 * 2 + kf) * 512 + l * 8);
            short8 al1 = *(const short8*)(sL + (1 * 2 + kf) * 512 + l * 8);
#pragma unroll
            for (int t = 0; t < 6; ++t) {
                int nt = w * 6 + t;
                short8 bh = *(const short8*)(fh + (size_t)(nt * 2 + kf) * 512 + l * 8);
                short8 bl = *(const short8*)(fl + (size_t)(nt * 2 + kf) * 512 + l * 8);
                acc[t][0] = __builtin_amdgcn_mfma_f32_16x16x32_bf16(ah0, bh, acc[t][0], 0, 0, 0);
                acc[t][0] = __builtin_amdgcn_mfma_f32_16x16x32_bf16(al0, bh, acc[t][0], 0, 0, 0);
                acc[t][0] = __builtin_amdgcn_mfma_f32_16x16x32_bf16(ah0, bl, acc[t][0], 0, 0, 0);
                acc[t][1] = __builtin_amdgcn_mfma_f32_16x16x32_bf16(ah1, bh, acc[t][1], 0, 0, 0);
                acc[t][1] = __builtin_amdgcn_mfma_f32_16x16x32_bf16(al1, bh, acc[t][1], 0, 0, 0);
                acc[t][1] = __builtin_amdgcn_mfma_f32_16x16x32_bf16(ah1, bl, acc[t][1], 0, 0, 0);
            }
        }
#pragma unroll
        for (int t = 0; t < 6; ++t) {
            int col = (w * 6 + t) * 16 + (l & 15);
            float bias = attn_in_b[col];
#pragma unroll
            for (int r = 0; r < 4; ++r) {
                int row = (l >> 4) * 4 + r;
                qkv[row * 200 + col] = acc[t][0][r] + bias;
            }
            if ((l >> 4) == 0) qkv[16 * 200 + col] = acc[t][1][0] + bias;
        }
    }
    __syncthreads();

    // Phase 3: scores via DPP 16-lane reduce, lane-local softmax, ctx.
    {
        int g = l >> 4;
        float kc[SEQL], vc[SEQL];
#pragma unroll
        for (int j = 0; j < SEQL; ++j) {
            kc[j] = qkv[j * 200 + 64 + g * 16 + (l & 15)];
            vc[j] = qkv[j * 200 + 128 + l];
        }
        for (int i = w * 8 + 1; i <= w * 8 + 8; ++i) {
            float qi = qkv[i * 200 + g * 16 + (l & 15)];
            float sj[SEQL];
#pragma unroll
            for (int j = 0; j < SEQL; ++j) {
                sj[j] = rsum16(qi * kc[j]) * 0.25f;
            }
            float m = sj[0];
#pragma unroll
            for (int j = 1; j < SEQL; ++j) m = fmaxf(m, sj[j]);
            float ssum = 0.f;
#pragma unroll
            for (int j = 0; j < SEQL; ++j) { sj[j] = __expf(sj[j] - m); ssum += sj[j]; }
            float inv = 1.f / ssum;
            float c = 0.f;
#pragma unroll
            for (int j = 0; j < SEQL; ++j) c += sj[j] * vc[j];
            c *= inv;
            unsigned short ch = f2bf(c);
            unsigned short cl = f2bf(c - bf2f(ch));
            int ls = ((i - 1) & 15) + (((l >> 3) & 3) << 4);
            int kf = l >> 5;
            int j2 = l & 7;
            size_t off = (size_t)kf * 512 + ls * 8 + j2;
            ctxH[off] = ch;
            ctxL[off] = cl;
        }
    }
    __syncthreads();

    // Phase 4: attn_out = ctx @ aow^T via MFMA (ao overlays sH/sL region)
    {
        const unsigned short* gh = (const unsigned short*)(ws + WS_AOWFH);
        const unsigned short* gl = (const unsigned short*)(ws + WS_AOWFL);
        f32x4 acc[2];
        acc[0] = (f32x4){0.f, 0.f, 0.f, 0.f};
        acc[1] = acc[0];
#pragma unroll
        for (int kf = 0; kf < 2; ++kf) {
            short8 ah = *(const short8*)(ctxH + kf * 512 + l * 8);
            short8 al = *(const short8*)(ctxL + kf * 512 + l * 8);
#pragma unroll
            for (int t = 0; t < 2; ++t) {
                int nt = w * 2 + t;
                short8 bh = *(const short8*)(gh + (size_t)(nt * 2 + kf) * 512 + l * 8);
                short8 bl = *(const short8*)(gl + (size_t)(nt * 2 + kf) * 512 + l * 8);
                acc[t] = __builtin_amdgcn_mfma_f32_16x16x32_bf16(ah, bh, acc[t], 0, 0, 0);
                acc[t] = __builtin_amdgcn_mfma_f32_16x16x32_bf16(al, bh, acc[t], 0, 0, 0);
                acc[t] = __builtin_amdgcn_mfma_f32_16x16x32_bf16(ah, bl, acc[t], 0, 0, 0);
            }
        }
        __syncthreads();
#pragma unroll
        for (int t = 0; t < 2; ++t) {
            int col = (w * 2 + t) * 16 + (l & 15);
            float bias = attn_out_b[col];
#pragma unroll
            for (int r = 0; r < 4; ++r) {
                int row = (l >> 4) * 4 + r;
                ao[row * 72 + col] = acc[t][r] + bias;
            }
        }
    }
    __syncthreads();

    // Phase 5: residual + LN + logits (wave w: e = w*8..w*8+7)
    float rs[SEQL];
#pragma unroll
    for (int i = 1; i < SEQL; ++i) rs[i] = seqc[i] + ao[(i - 1) * 72 + l];

    float c1 = ln_w[l] * ls_w[l];
    float c1sum = rsum64(c1);
    float c0sum = rsum64(ln_b[l] * ls_w[l]);
    float lsb0 = ls_b[0];
#pragma unroll
    for (int ee = 0; ee < 8; ++ee) {
        int e = w * 8 + ee;
        float x = rs[e + 1];
        float s1 = rsum64(x);
        float s2 = rsum64(x * x);
        float s3 = rsum64(x * c1);
        float mu = s1 * (1.0f / DLQ);
        float var = s2 * (1.0f / DLQ) - mu * mu;
        float rstd = rsqrtf(var + 1e-5f);
        float lgv = rstd * (s3 - mu * c1sum) + c0sum + lsb0 + ws[WS_GB + b * NE + e];
        if (l == 0) lgv_sh[e] = lgv;
    }
    __syncthreads();

    // softmax + top2 (only wave 0 commits)
    if (w == 0) {
        float p[NE];
        float lgv[NE];
#pragma unroll
        for (int e = 0; e < NE; ++e) lgv[e] = lgv_sh[e];
        float m = lgv[0];
#pragma unroll
        for (int e = 1; e < NE; ++e) m = fmaxf(m, lgv[e]);
        float ssum = 0.f;
#pragma unroll
        for (int e = 0; e < NE; ++e) { p[e] = __expf(lgv[e] - m); ssum += p[e]; }
        float inv = 1.f / ssum;
#pragma unroll
        for (int e = 0; e < NE; ++e) p[e] *= inv;
        int t0 = 0; float b0 = p[0];
#pragma unroll
        for (int e = 1; e < NE; ++e) if (p[e] > b0) { b0 = p[e]; t0 = e; }
        int t1 = -1; float b1 = -1.f;
#pragma unroll
        for (int e = 0; e < NE; ++e) if (e != t0 && p[e] > b1) { b1 = p[e]; t1 = e; }

        float sw = b0 + b1;
        float tw0 = b0 / sw, tw1 = b1 / sw;
        // ACT epilogue: gelu(ef of selected experts) * weight, bf16
        unsigned short* actp = (unsigned short*)(ws + WS_ACT);
        float efv0 = ws[WS_EF + (size_t)n * DMODEL + t0 * DLQ + l] +
                     ws[WS_P1 + (size_t)n * DMODEL + t0 * DLQ + l];
        float efv1 = ws[WS_EF + (size_t)n * DMODEL + t1 * DLQ + l] +
                     ws[WS_P1 + (size_t)n * DMODEL + t1 * DLQ + l];
        actp[(size_t)(n * 2 + 0) * 64 + l] = f2bf(gelu_exact(efv0) * tw0);
        actp[(size_t)(n * 2 + 1) * 64 + l] = f2bf(gelu_exact(efv1) * tw1);
        if (l == 0) {
#pragma unroll
            for (int e = 0; e < NE; ++e) ws[WS_PR + (size_t)n * NE + e] = p[e];
            ((int*)(ws + WS_TI))[n] = t0 | (t1 << 8);
        }
    }
}

// K4 (fused): blocks (e<16, ct): expert-major MoE GEMM. B-frags converted
// inline from fp32 w_up (w_up read exactly once, coalesced in 16-lane groups).
// Ballot-compacted local token list, MFMA, atomicAdd into memset-zeroed out.
// Block (16, 0): aux loss.
__global__ __launch_bounds__(256) void k_moe_gemm(const float* __restrict__ w_up,
                                                  float* __restrict__ ws,
                                                  float* __restrict__ out) {
    __shared__ int lst[2048];
    __shared__ int lcnt;
    __shared__ float wsum[4][NE];
    __shared__ int hist[NE];
    int tid = threadIdx.x;
    int wv = tid >> 6, l = tid & 63;

    if (blockIdx.x == NE) {
        if (blockIdx.y != 0) return;
        if (tid < NE) hist[tid] = 0;
        __syncthreads();
        {
            const int* tip = (const int*)(ws + WS_TI);
#pragma unroll
            for (int c = 0; c < 4; ++c) {
                int pk = tip[tid * 4 + c];
                atomicAdd(&hist[pk & 0xff], 1);
                atomicAdd(&hist[(pk >> 8) & 0xff], 1);
            }
        }
        float p[NE];
#pragma unroll
        for (int e = 0; e < NE; ++e) p[e] = 0.f;
        const float* pr = ws + WS_PR + (size_t)tid * 64;
#pragma unroll
        for (int r = 0; r < 4; ++r)
#pragma unroll
            for (int q = 0; q < 4; ++q) {
                float4 v = *(const float4*)(pr + r * 16 + q * 4);
                p[q * 4 + 0] += v.x; p[q * 4 + 1] += v.y;
                p[q * 4 + 2] += v.z; p[q * 4 + 3] += v.w;
            }
#pragma unroll
        for (int e = 0; e < NE; ++e) p[e] = rsum64(p[e]);
        if (l == 0) {
#pragma unroll
            for (int e = 0; e < NE; ++e) wsum[wv][e] = p[e];
        }
        __syncthreads();
        if (tid == 0) {
            float s = 0.f;
#pragma unroll
            for (int e = 0; e < NE; ++e) {
                float sp = wsum[0][e] + wsum[1][e] + wsum[2][e] + wsum[3][e];
                s += sp * (float)hist[e];
            }
            out[(size_t)NTOK * DMODEL] = (float)NE * s / ((float)NTOK * (float)NTOK);
        }
        return;
    }

    // ---- MoE GEMM ----
    int e = blockIdx.x, ct = blockIdx.y;
    if (tid == 0) lcnt = 0;
    __syncthreads();
    {
        const int* tip = (const int*)(ws + WS_TI);
#pragma unroll
        for (int c = 0; c < 4; ++c) {
            int tok = wv * 256 + c * 64 + l;
            int pk = tip[tok];
            bool m1 = ((pk >> 8) & 0xff) == e;
            bool m = ((pk & 0xff) == e) || m1;
            unsigned long long mask = __ballot(m);
            int base = 0;
            if (l == 0 && mask) base = atomicAdd(&lcnt, __popcll(mask));
            base = __shfl(base, 0);
            if (m) {
                int pos = base + __popcll(mask & ((1ull << l) - 1ull));
                lst[pos] = tok * 2 + (m1 ? 1 : 0);
            }
        }
    }
    __syncthreads();
    int cnt = lcnt;
    if (cnt == 0) return;

    // Inline B-frag conversion: lane needs w_up[e][kb+j][col], j=0..7 (+32)
    int col = ct * 64 + wv * 16 + (l & 15);
    int kb = (l >> 4) * 8;
    const float* wue = w_up + (size_t)e * DLQ * DMODEL + col;
    unsigned short b0v[8], b1v[8];
#pragma unroll
    for (int j = 0; j < 8; ++j) {
        b0v[j] = f2bf(wue[(size_t)(kb + j) * DMODEL]);
        b1v[j] = f2bf(wue[(size_t)(kb + 32 + j) * DMODEL]);
    }
    short8 bf0 = *(short8*)b0v;
    short8 bf1 = *(short8*)b1v;

    const unsigned short* actp = (const unsigned short*)(ws + WS_ACT);
    int cr = (l >> 4) * 4;

    for (int mt = 0; mt < cnt; mt += 16) {
        int row = mt + (l & 15);
        short8 a0 = {0, 0, 0, 0, 0, 0, 0, 0};
        short8 a1 = {0, 0, 0, 0, 0, 0, 0, 0};
        if (row < cnt) {
            int pk = lst[row];
            a0 = *(const short8*)(actp + (size_t)pk * 64 + kb);
            a1 = *(const short8*)(actp + (size_t)pk * 64 + 32 + kb);
        }
        f32x4 acc = {0.f, 0.f, 0.f, 0.f};
        acc = __builtin_amdgcn_mfma_f32_16x16x32_bf16(a0, bf0, acc, 0, 0, 0);
        acc = __builtin_amdgcn_mfma_f32_16x16x32_bf16(a1, bf1, acc, 0, 0, 0);
#pragma unroll
        for (int r = 0; r < 4; ++r) {
            int rr = mt + cr + r;
            if (rr < cnt) {
                int pk = lst[rr];
                atomicAdd(&out[(size_t)(pk >> 1) * DMODEL + col], acc[r]);
            }
        }
    }
}

extern "C" void kernel_launch(void* const* d_in, const int* in_sizes, int n_in,
                              void* d_out, int out_size, void* d_ws, size_t ws_size,
                              hipStream_t stream) {
    const float* x          = (const float*)d_in[0];
    const float* w_down     = (const float*)d_in[1];
    const float* pos_embed  = (const float*)d_in[2];
    const float* gp_w       = (const float*)d_in[3];
    const float* gp_b       = (const float*)d_in[4];
    const float* attn_in_w  = (const float*)d_in[5];
    const float* attn_in_b  = (const float*)d_in[6];
    const float* attn_out_w = (const float*)d_in[7];
    const float* attn_out_b = (const float*)d_in[8];
    const float* ln_w       = (const float*)d_in[9];
    const float* ln_b       = (const float*)d_in[10];
    const float* ls_w       = (const float*)d_in[11];
    const float* ls_b       = (const float*)d_in[12];
    const float* g1_w       = (const float*)d_in[13];
    const float* g1_b       = (const float*)d_in[14];
    const float* g2_w       = (const float*)d_in[15];
    const float* g2_b       = (const float*)d_in[16];
    const float* w_up       = (const float*)d_in[17];
    float* ws  = (float*)d_ws;
    float* out = (float*)d_out;

    hipMemsetAsync(out, 0, (size_t)out_size * sizeof(float), stream);
    k_prep<<<1057, 256, 0, stream>>>(x, w_down, gp_w, attn_in_w, attn_out_w, ws);
    k_ef_mfma<<<544, 256, 0, stream>>>(ws);
    k_gctx<<<NB, 256, 0, stream>>>(gp_b, g1_w, g1_b, g2_w, g2_b, ws);
    k_attn2<<<NTOK, 128, 0, stream>>>(pos_embed, attn_in_b, attn_out_b,
                                      ln_w, ln_b, ls_w, ls_b, ws);
    k_moe_gemm<<<dim3(NE + 1, 16), 256, 0, stream>>>(w_up, ws, out);
}